// Round 1
// baseline (91.787 us; speedup 1.0000x reference)
//
#include <hip/hip_runtime.h>

// Problem constants (match reference)
constexpr int Bb  = 4;
constexpr int C   = 64;
constexpr int H   = 128;
constexpr int Wd  = 128;
constexpr int K   = 5;
constexpr int LOC = 2;
constexpr int KK  = K * K;        // 25
constexpr int CKK = C * KK;       // 1600
constexpr int HW  = H * Wd;       // 16384
constexpr int N   = Bb * C * HW;  // 4194304 per output tensor

typedef float v4f __attribute__((ext_vector_type(4)));

__device__ __forceinline__ float frcp(float x) { return __builtin_amdgcn_rcpf(x); }
__device__ __forceinline__ void nt_store4(float* p, v4f v) {
    __builtin_nontemporal_store(v, reinterpret_cast<v4f*>(p));
}

// Fused chansum + 5x5 box + clamp + reciprocal:
//   RM[b,h,w] = 1 / max(box5x5(sum_c x), K)
// 256 blocks x 768 threads. Channel sum is 4-way split (16-deep serial chains
// instead of 64) and combined through LDS; x is binary so every partial sum is
// a small integer -> bit-exact under any summation order. 12 waves/block for
// latency hiding (v1 had 3 active waves with 64-deep chains: latency-bound).
__global__ void __launch_bounds__(768) k_prep(const float* __restrict__ x,
                                              float* __restrict__ RM) {
    __shared__ float P[4][6][Wd];   // partial chansums (12 KB)
    __shared__ float S[6][Wd];      // combined chansum rows (3 KB)
    const int t = threadIdx.x;
    const int b = blockIdx.x >> 6;
    const int strip = blockIdx.x & 63;
    const int r0 = strip * 2;              // output rows r0, r0+1

    // Phase 1: 768 threads = 192 v4-slots (6 rows x 32 cols) x 4 channel chunks.
    {
        const int chunk = t / 192;         // 0..3 -> channels [16*chunk, 16*chunk+16)
        const int slot  = t - chunk * 192; // 0..191
        const int lr = slot >> 5;          // 0..5 -> global row r0-2+lr
        const int c0 = (slot & 31) * 4;
        const int gr = r0 - 2 + lr;
        v4f s = {0.f, 0.f, 0.f, 0.f};
        if ((unsigned)gr < (unsigned)H) {
            const float* p = x + (((size_t)b * C + chunk * 16) * H + gr) * Wd + c0;
#pragma unroll
            for (int c = 0; c < 16; ++c)
                s += *reinterpret_cast<const v4f*>(p + (size_t)c * HW);
        }
        *reinterpret_cast<v4f*>(&P[chunk][lr][c0]) = s;
    }
    __syncthreads();

    // Phase 1b: combine the 4 channel chunks (exact: integer values).
    if (t < 192) {
        const int lr = t >> 5;
        const int c0 = (t & 31) * 4;
        v4f s = *reinterpret_cast<v4f*>(&P[0][lr][c0])
              + *reinterpret_cast<v4f*>(&P[1][lr][c0])
              + *reinterpret_cast<v4f*>(&P[2][lr][c0])
              + *reinterpret_cast<v4f*>(&P[3][lr][c0]);
        *reinterpret_cast<v4f*>(&S[lr][c0]) = s;
    }
    __syncthreads();

    // Phase 2: one thread per output pixel (2 rows x 128 cols).
    if (t < 256) {
        const int lr = t >> 7;             // 0..1
        const int w  = t & 127;
        const int gr = r0 + lr;
        float s = 0.f;
#pragma unroll
        for (int j = 0; j < K; ++j) {
            const float* row = S[lr + j];  // global row gr + j - 2 (zeroed if OOB)
#pragma unroll
            for (int kk = 0; kk < K; ++kk) {
                const int ww = w + kk - LOC;
                if ((unsigned)ww < (unsigned)Wd) s += row[ww];
            }
        }
        RM[b * HW + gr * Wd + w] = frcp(fmaxf(s, (float)K));
    }
}

// One block per (b,o) plane, 1024 threads. Taps packed into int4 in LDS
// (single ds_read_b128 per tap). Aligned v4f fast path for dk==0 taps
// (wave-uniform branch; the one-hot weights always hit it). RM (=1/M) loads
// issued before Phase A so their latency hides under the weight decode.
__global__ void __launch_bounds__(1024) k_main(
    const float* __restrict__ x, const float* __restrict__ wgt,
    const float* __restrict__ RM, float* __restrict__ out0,
    float* __restrict__ out1, float* __restrict__ out2) {
    __shared__ int4  s_tap[CKK];    // {c*HW + dj*Wd, dj, dk, float_bits(v)} (25.6 KB)
    __shared__ int   s_cnt;
    __shared__ float s_wsum;
    __shared__ float s_red[16];
    __shared__ float s_rinv;

    const int tid = threadIdx.x;
    const int plane = blockIdx.x;          // b*C + o
    const int o = plane & (C - 1);
    const int b = plane >> 6;

    const float* xb  = x + (size_t)b * C * HW;
    const float* RMb = RM + b * HW;

    // Issue all 16 RM loads up front; consumed after Phase A.
    v4f rm[4];
#pragma unroll
    for (int it = 0; it < 4; ++it)
        rm[it] = *reinterpret_cast<const v4f*>(RMb + it * 4096 + tid * 4);

    if (tid == 0) { s_cnt = 0; s_wsum = 0.0f; }
    __syncthreads();

    // Phase A: compact + decode nonzero taps of W row o into LDS.
    const float* wrow = wgt + o * CKK;
    for (int k = tid; k < CKK; k += 1024) {
        float v = wrow[k];
        if (v != 0.0f) {
            int pos = atomicAdd(&s_cnt, 1);
            const int c  = k / KK;
            const int r  = k - c * KK;
            const int rj = r / K;
            const int dj = rj - LOC;
            const int dk = (r - rj * K) - LOC;
            int4 tp;
            tp.x = c * HW + dj * Wd;
            tp.y = dj;
            tp.z = dk;
            tp.w = __float_as_int(v);
            s_tap[pos] = tp;
            atomicAdd(&s_wsum, v);
        }
    }
    __syncthreads();
    const int   n   = s_cnt;
    const float rws = frcp(1e-10f + s_wsum);

    float* o0 = out0 + (size_t)plane * HW;
    float* o1 = out1 + (size_t)plane * HW;
    float* o2 = out2 + (size_t)plane * HW;

    v4f tt[4];
    float lmax = -INFINITY;
#pragma unroll
    for (int it = 0; it < 4; ++it) {
        const int p = it * 4096 + tid * 4;   // 4 consecutive px, same row (4|Wd)
        const int h = p >> 7, w = p & 127;
        v4f acc = {0.f, 0.f, 0.f, 0.f};
        for (int e = 0; e < n; ++e) {
            const int4 tp = s_tap[e];        // one ds_read_b128
            const float v = __int_as_float(tp.w);
            const int hh = h + tp.y;
            if ((unsigned)hh < (unsigned)H) {
                if (tp.z == 0) {
                    // dk==0: aligned, never OOB in w -> single v4f load.
                    // addr = xb + tp.x + h*Wd + w = xb + tp.x + p
                    const v4f xv = *reinterpret_cast<const v4f*>(xb + tp.x + p);
                    acc.x += v * xv.x; acc.y += v * xv.y;
                    acc.z += v * xv.z; acc.w += v * xv.w;
                } else {
                    const float* rowp = xb + tp.x + h * Wd;
                    const int wb = w + tp.z;
                    float x0 = ((unsigned)(wb + 0) < (unsigned)Wd) ? rowp[wb + 0] : 0.f;
                    float x1 = ((unsigned)(wb + 1) < (unsigned)Wd) ? rowp[wb + 1] : 0.f;
                    float x2 = ((unsigned)(wb + 2) < (unsigned)Wd) ? rowp[wb + 2] : 0.f;
                    float x3 = ((unsigned)(wb + 3) < (unsigned)Wd) ? rowp[wb + 3] : 0.f;
                    acc.x += v * x0; acc.y += v * x1; acc.z += v * x2; acc.w += v * x3;
                }
            }
        }
        nt_store4(o0 + p, acc);
        v4f tv;
        tv.x = acc.x * rm[it].x * rws;
        tv.y = acc.y * rm[it].y * rws;
        tv.z = acc.z * rm[it].z * rws;
        tv.w = acc.w * rm[it].w * rws;
        tt[it] = tv;
        lmax = fmaxf(lmax, fmaxf(fmaxf(tv.x, tv.y), fmaxf(tv.z, tv.w)));
    }

    // Plane max: wave butterfly, then LDS combine across 16 waves.
#pragma unroll
    for (int m = 32; m > 0; m >>= 1) lmax = fmaxf(lmax, __shfl_xor(lmax, m, 64));
    if ((tid & 63) == 0) s_red[tid >> 6] = lmax;
    __syncthreads();
    if (tid == 0) {
        float r = s_red[0];
#pragma unroll
        for (int q = 1; q < 16; ++q) r = fmaxf(r, s_red[q]);
        s_rinv = frcp(1e-10f + r);
    }
    __syncthreads();
    const float rinv = s_rinv;

#pragma unroll
    for (int it = 0; it < 4; ++it) {
        const int p = it * 4096 + tid * 4;
        const v4f tv = tt[it];
        v4f xn, bn;
        xn = tv * rinv;
        bn.x = (xn.x * xn.x * xn.x >= 0.5f) ? 1.f : 0.f;
        bn.y = (xn.y * xn.y * xn.y >= 0.5f) ? 1.f : 0.f;
        bn.z = (xn.z * xn.z * xn.z >= 0.5f) ? 1.f : 0.f;
        bn.w = (xn.w * xn.w * xn.w >= 0.5f) ? 1.f : 0.f;
        nt_store4(o1 + p, xn);
        nt_store4(o2 + p, bn);
    }
}

extern "C" void kernel_launch(void* const* d_in, const int* in_sizes, int n_in,
                              void* d_out, int out_size, void* d_ws, size_t ws_size,
                              hipStream_t stream) {
    const float* x   = (const float*)d_in[0];
    const float* wgt = (const float*)d_in[1];
    float* out = (float*)d_out;
    float* RMw = (float*)d_ws;    // [Bb*HW] reciprocal of clamped box sum

    float* out0 = out;            // x_lateral
    float* out1 = out + N;        // xn
    float* out2 = out + 2 * N;    // x_lateral_bin

    k_prep<<<Bb * 64, 768, 0, stream>>>(x, RMw);
    k_main<<<Bb * C, 1024, 0, stream>>>(x, wgt, RMw, out0, out1, out2);
}